// Round 5
// baseline (143.826 us; speedup 1.0000x reference)
//
#include <hip/hip_runtime.h>

// CRF forward (log-partition) — B=1024, T=512, K=64. One wave per batch.
// Exp-domain recurrence keeps exp/log OFF the serial chain:
//   u[i] = exp(alpha[i] - C);  step: u <- (E·u) * F,  F = exp(emit - 4.5)
// Broadcast of u via LDS (single wave: DS ops are in-order -> no barrier,
// and even a single buffer is RAW/WAR safe).
//
// R4 lesson: VGPR_Count=72 proved the unrolled arrays (Epk/wreg/acc) were
// NOT promoted to registers -> E reloaded from scratch every step, on the
// critical chain. This round: every per-step value is an individually
// NAMED variable (macro-expanded) so scratch allocation is impossible;
// __launch_bounds__(64,1) gives the 512-VGPR budget (we only want
// 1 wave/SIMD anyway: 1024 chains on 1024 SIMDs).

constexpr int CRF_B = 1024;
constexpr int CRF_T = 512;
constexpr int CRF_K = 64;

typedef float v2f __attribute__((ext_vector_type(2)));

__device__ __forceinline__ float bcast_lane(float v, int lane) {
    return __int_as_float(__builtin_amdgcn_readlane(__float_as_int(v), lane));
}

#define FOREACH16(X) X(0) X(1) X(2) X(3) X(4) X(5) X(6) X(7) \
                     X(8) X(9) X(10) X(11) X(12) X(13) X(14) X(15)

__global__ __launch_bounds__(64, 1) void crf_forward_kernel(
    const float* __restrict__ feats,      // [B, T, K]
    const float* __restrict__ trans,      // [K, K]
    const int*   __restrict__ seq_lens,   // [B]
    float*       __restrict__ out)        // [B]
{
    const int b    = blockIdx.x;
    const int lane = threadIdx.x;
    constexpr float G = 4.5f;             // per-step growth bias (baked into F)

    __shared__ __align__(16) float wbuf[CRF_K];

    // E[lane][j] = exp(trans[lane][j]) in 32 NAMED packed-f32 registers.
    const float4* trow = (const float4*)(trans + lane * CRF_K);
#define DECL_INIT_E(q)                                        \
    v2f Elo##q, Ehi##q;                                       \
    {                                                         \
        const float4 t4 = trow[q];                            \
        Elo##q = v2f{__expf(t4.x), __expf(t4.y)};             \
        Ehi##q = v2f{__expf(t4.z), __expf(t4.w)};             \
    }
    FOREACH16(DECL_INIT_E)

    const int L   = seq_lens[b];          // uniform across the wave
    const int Lm1 = L - 1;
    const float* fb = feats + (size_t)b * CRF_T * CRF_K + lane;

    // t = 0 init (exp domain).
    const float fv0 = fb[0];
    const float m0  = bcast_lane(fv0, 0);
    float u = __expf(fv0 - m0);
    float C = m0;

    // Emission prefetch: p2 = emit[t+1], p3 = emit[t+2] at loop top.
    float p2 = fb[(size_t)min(2, Lm1) * CRF_K];
    float p3 = fb[(size_t)min(3, Lm1) * CRF_K];
    float Fc = __expf(fb[(size_t)min(1, Lm1) * CRF_K] - G);   // factor for t=1

    for (int t = 1; t < L; ++t) {
        const float Fn = __expf(p2 - G);  // factor for t+1 — off the u-chain
        p2 = p3;
        p3 = fb[(size_t)min(t + 3, Lm1) * CRF_K];   // prefetch t+3 (clamped)

        wbuf[lane] = u;                   // ds_write; in-order with reads below
        const float4* src = (const float4*)wbuf;

        // 16 broadcast ds_read_b128 into NAMED registers, clustered.
#define DECL_LOAD_W(q) const float4 w##q = src[q];
        FOREACH16(DECL_LOAD_W)
        __builtin_amdgcn_sched_barrier(0);

        // 32 packed FMAs on 8 NAMED accumulator chains.
        v2f acc0{0.f, 0.f}, acc1{0.f, 0.f}, acc2{0.f, 0.f}, acc3{0.f, 0.f};
        v2f acc4{0.f, 0.f}, acc5{0.f, 0.f}, acc6{0.f, 0.f}, acc7{0.f, 0.f};
#define FMA_Q(q, a, bidx)                                                     \
        acc##a    = __builtin_elementwise_fma(Elo##q, v2f{w##q.x, w##q.y}, acc##a); \
        acc##bidx = __builtin_elementwise_fma(Ehi##q, v2f{w##q.z, w##q.w}, acc##bidx);
        FMA_Q(0, 0, 1)  FMA_Q(1, 2, 3)  FMA_Q(2, 4, 5)  FMA_Q(3, 6, 7)
        FMA_Q(4, 0, 1)  FMA_Q(5, 2, 3)  FMA_Q(6, 4, 5)  FMA_Q(7, 6, 7)
        FMA_Q(8, 0, 1)  FMA_Q(9, 2, 3)  FMA_Q(10, 4, 5) FMA_Q(11, 6, 7)
        FMA_Q(12, 0, 1) FMA_Q(13, 2, 3) FMA_Q(14, 4, 5) FMA_Q(15, 6, 7)
#undef FMA_Q

        const v2f s01 = acc0 + acc1, s23 = acc2 + acc3;
        const v2f s45 = acc4 + acc5, s67 = acc6 + acc7;
        const v2f sv  = (s01 + s23) + (s45 + s67);
        u = (sv.x + sv.y) * Fc;

        if ((t & 7) == 0) {               // periodic rescale; log is off-chain
            const float m = bcast_lane(u, 0);
            const float r = __builtin_amdgcn_rcpf(m);
            u *= r;
            C += __logf(m);
        }
        Fc = Fn;
    }

    C += G * (float)Lm1;                  // restore the baked bias

    // Final LSE over lanes: out = C + log(sum_i u[i]).
    float e = u;
#pragma unroll
    for (int off = 32; off > 0; off >>= 1) e += __shfl_xor(e, off, 64);
    if (lane == 0) out[b] = C + __logf(e);
}

extern "C" void kernel_launch(void* const* d_in, const int* in_sizes, int n_in,
                              void* d_out, int out_size, void* d_ws, size_t ws_size,
                              hipStream_t stream)
{
    const float* feats    = (const float*)d_in[0];
    const float* trans    = (const float*)d_in[1];
    const int*   seq_lens = (const int*)d_in[2];
    float*       out      = (float*)d_out;

    crf_forward_kernel<<<dim3(CRF_B), dim3(CRF_K), 0, stream>>>(
        feats, trans, seq_lens, out);
}

// Round 6
// 95.718 us; speedup vs baseline: 1.5026x; 1.5026x over previous
//
#include <hip/hip_runtime.h>

// CRF forward (log-partition) — B=1024, T=512, K=64. One wave per batch.
// Exp-domain recurrence: u[i] = exp(alpha[i] - C); step u <- (E·u) * F,
// F = exp(emit - 4.5) computed OFF the serial chain from prefetched
// emissions. Broadcast of u via single-buffer LDS (single wave: DS ops are
// in-order -> no barrier, RAW/WAR safe).
//
// R5 lesson: VGPR_Count stayed 72 => the register ALLOCATOR still targets
// max occupancy (launch_bounds' 2nd arg only sets a waves-per-eu MINIMUM)
// and spills the 64-reg E matrix, reloading it every step. Fix:
// amdgpu_waves_per_eu(1,1) pins the occupancy target to 1 wave/EU (grid is
// exactly 1 wave/SIMD anyway) -> full 512-VGPR budget.
// Also: t-loop chunked by 8 so emission-prefetch vmcnt waits and the
// rescale amortize over 8 steps.

constexpr int CRF_B = 1024;
constexpr int CRF_T = 512;
constexpr int CRF_K = 64;

typedef float v2f __attribute__((ext_vector_type(2)));

__device__ __forceinline__ float bcast_lane(float v, int lane) {
    return __int_as_float(__builtin_amdgcn_readlane(__float_as_int(v), lane));
}

#define FOREACH8(X)  X(0) X(1) X(2) X(3) X(4) X(5) X(6) X(7)
#define FOREACH16(X) X(0) X(1) X(2) X(3) X(4) X(5) X(6) X(7) \
                     X(8) X(9) X(10) X(11) X(12) X(13) X(14) X(15)

// One recurrence step: u <- (E · broadcast(u)) * Fv.
#define LOADW(q) const float4 w##q = src[q];
#define FMA_Q(q, a, b2)                                                        \
    acc##a  = __builtin_elementwise_fma(Elo##q, v2f{w##q.x, w##q.y}, acc##a);  \
    acc##b2 = __builtin_elementwise_fma(Ehi##q, v2f{w##q.z, w##q.w}, acc##b2);
#define STEP(Fv)                                                               \
    do {                                                                       \
        wbuf[lane] = u;                                                        \
        const float4* src = (const float4*)wbuf;                               \
        FOREACH16(LOADW)                                                       \
        v2f acc0{0.f,0.f}, acc1{0.f,0.f}, acc2{0.f,0.f}, acc3{0.f,0.f};        \
        v2f acc4{0.f,0.f}, acc5{0.f,0.f}, acc6{0.f,0.f}, acc7{0.f,0.f};        \
        FMA_Q(0,0,1)  FMA_Q(1,2,3)  FMA_Q(2,4,5)  FMA_Q(3,6,7)                 \
        FMA_Q(4,0,1)  FMA_Q(5,2,3)  FMA_Q(6,4,5)  FMA_Q(7,6,7)                 \
        FMA_Q(8,0,1)  FMA_Q(9,2,3)  FMA_Q(10,4,5) FMA_Q(11,6,7)                \
        FMA_Q(12,0,1) FMA_Q(13,2,3) FMA_Q(14,4,5) FMA_Q(15,6,7)                \
        const v2f s01 = acc0 + acc1, s23 = acc2 + acc3;                        \
        const v2f s45 = acc4 + acc5, s67 = acc6 + acc7;                        \
        const v2f sv  = (s01 + s23) + (s45 + s67);                             \
        u = (sv.x + sv.y) * (Fv);                                              \
    } while (0)

__global__ __launch_bounds__(64)
__attribute__((amdgpu_waves_per_eu(1, 1)))
void crf_forward_kernel(
    const float* __restrict__ feats,      // [B, T, K]
    const float* __restrict__ trans,      // [K, K]
    const int*   __restrict__ seq_lens,   // [B]
    float*       __restrict__ out)        // [B]
{
    const int b    = blockIdx.x;
    const int lane = threadIdx.x;
    constexpr float G = 4.5f;             // per-step growth bias (baked into F)

    __shared__ __align__(16) float wbuf[CRF_K];

    // E[lane][j] = exp(trans[lane][j]) in 32 NAMED packed-f32 registers.
    const float4* trow = (const float4*)(trans + lane * CRF_K);
#define DECL_INIT_E(q)                                        \
    v2f Elo##q, Ehi##q;                                       \
    {                                                         \
        const float4 t4 = trow[q];                            \
        Elo##q = v2f{__expf(t4.x), __expf(t4.y)};             \
        Ehi##q = v2f{__expf(t4.z), __expf(t4.w)};             \
    }
    FOREACH16(DECL_INIT_E)

    const int L   = seq_lens[b];          // uniform across the wave
    const int Lm1 = L - 1;
    const float* fb = feats + (size_t)b * CRF_T * CRF_K + lane;

    // t = 0 init (exp domain).
    const float fv0 = fb[0];
    const float m0  = bcast_lane(fv0, 0);
    float u = __expf(fv0 - m0);
    float C = m0;

    // r##q holds the raw emission for step (t + q). Prologue: steps 1..8.
#define DECL_R(q) float r##q = fb[(size_t)min(1 + q, Lm1) * CRF_K];
    FOREACH8(DECL_R)

    int t = 1;
    while (t + 8 <= L) {                  // full chunk: steps t .. t+7
        // Factors for THIS chunk from r (loaded a whole chunk ago ->
        // any vmcnt wait here is against long-arrived loads).
#define MKF(q) const float F##q = __expf(r##q - G);
        FOREACH8(MKF)
        // Prefetch next chunk's raw emissions (steps t+8 .. t+15, clamped).
#define RELOAD_R(q) r##q = fb[(size_t)min(t + 8 + q, Lm1) * CRF_K];
        FOREACH8(RELOAD_R)

        STEP(F0); STEP(F1); STEP(F2); STEP(F3);
        STEP(F4); STEP(F5); STEP(F6); STEP(F7);

        {   // once-per-chunk rescale; log is off the u-chain (feeds only C)
            const float m = bcast_lane(u, 0);
            u *= __builtin_amdgcn_rcpf(m);
            C += __logf(m);
        }
        t += 8;
    }

    // Tail: < 8 steps, factors from the resident r registers (no loads).
#define TAILSTEP(q) if (t + q < L) { STEP(__expf(r##q - G)); }
    FOREACH8(TAILSTEP)

    C += G * (float)Lm1;                  // restore the baked bias

    // Final LSE over lanes: out = C + log(sum_i u[i]).
    float e = u;
#pragma unroll
    for (int off = 32; off > 0; off >>= 1) e += __shfl_xor(e, off, 64);
    if (lane == 0) out[b] = C + __logf(e);
}

extern "C" void kernel_launch(void* const* d_in, const int* in_sizes, int n_in,
                              void* d_out, int out_size, void* d_ws, size_t ws_size,
                              hipStream_t stream)
{
    const float* feats    = (const float*)d_in[0];
    const float* trans    = (const float*)d_in[1];
    const int*   seq_lens = (const int*)d_in[2];
    float*       out      = (float*)d_out;

    crf_forward_kernel<<<dim3(CRF_B), dim3(CRF_K), 0, stream>>>(
        feats, trans, seq_lens, out);
}